// Round 4
// baseline (287.198 us; speedup 1.0000x reference)
//
#include <hip/hip_runtime.h>
#include <hip/hip_bf16.h>
#include <stdint.h>

typedef __attribute__((ext_vector_type(4))) float f32x4;
typedef _Float16 f16;
typedef __attribute__((ext_vector_type(8))) _Float16 f16x8;
typedef decltype(__builtin_amdgcn_cvt_pkrtz(0.f, 0.f)) pk16;

#define DIM   768
#define NH    12
#define HD    64
#define NB    8
#define SEQ   512
#define SCALE 0.125f

#define MFMA16H __builtin_amdgcn_mfma_f32_16x16x32_f16

// gelu tanh-approx: x * sigmoid(2*0.7978845608*(x + 0.044715 x^3))
//   = x * rcp(1 + exp2(x*(-2.3022077 - 0.1029433 x^2)))
__device__ __forceinline__ float gelu_f(float x) {
    float pp = x * x;
    float poly = __builtin_fmaf(pp, -0.1029433f, -2.3022077f);
    float ev = __builtin_amdgcn_exp2f(x * poly);
    return x * __builtin_amdgcn_rcpf(1.0f + ev);
}

// ---------------- prep: f32 -> f16 convert (8 elems/thread) ----------------
__global__ void k_cvt16(const float* __restrict__ in, f16* __restrict__ out, int n8) {
    int i = blockIdx.x * blockDim.x + threadIdx.x;
    if (i >= n8) return;
    const float4* s = reinterpret_cast<const float4*>(in + i * 8);
    float4 f0 = s[0], f1 = s[1];
    union { pk16 h[4]; uint4 v; } o;
    o.h[0] = __builtin_amdgcn_cvt_pkrtz(f0.x, f0.y);
    o.h[1] = __builtin_amdgcn_cvt_pkrtz(f0.z, f0.w);
    o.h[2] = __builtin_amdgcn_cvt_pkrtz(f1.x, f1.y);
    o.h[3] = __builtin_amdgcn_cvt_pkrtz(f1.z, f1.w);
    reinterpret_cast<uint4*>(out)[i] = o.v;
}

// ---------------- prep: W[768][768] f32 -> WT[768][768] f16 (transposed) ----------------
__global__ void k_wt(const float* __restrict__ W, f16* __restrict__ WT) {
    __shared__ float t[32][33];
    int n0 = blockIdx.x * 32, k0 = blockIdx.y * 32;
    int tx = threadIdx.x, ty = threadIdx.y; // 32 x 8
#pragma unroll
    for (int j = 0; j < 4; ++j)
        t[ty + 8 * j][tx] = W[(k0 + ty + 8 * j) * DIM + n0 + tx];
    __syncthreads();
#pragma unroll
    for (int j = 0; j < 4; ++j)
        WT[(n0 + ty + 8 * j) * DIM + k0 + tx] = (f16)t[tx][ty + 8 * j];
}

// ---------------- prep: pack MLP param tables (f16 MFMA fragments) ----------------
__global__ void k_pack3(const float* __restrict__ W1, const float* __restrict__ b1,
                        const float* __restrict__ W2, f16* __restrict__ W1tab,
                        f16* __restrict__ W2tab) {
    int i = blockIdx.x * 256 + threadIdx.x;
    if (i < 3072) {
        int lane = i & 63;
        int hi = lane >> 4, m = lane & 15;
        int u = (i >> 6) * 16 + m;
#pragma unroll
        for (int e = 0; e < 8; ++e) {
            float v = 0.f;
            if (hi == 0) {
                if (e < 6) v = W1[e * DIM + u];
                else if (e == 6) v = b1[u];
            }
            W1tab[i * 8 + e] = (f16)v;
        }
    } else if (i < 4608) {
        int i2 = i - 3072;
        int j = i2 >> 6, lane = i2 & 63;
        int g = lane >> 4, h = lane & 15;
#pragma unroll
        for (int e = 0; e < 8; ++e) {
            int u = 32 * j + ((e >> 2) << 4) + (g << 2) + (e & 3);
            float v = (h < 12) ? W2[u * 12 + h] : 0.f;
            W2tab[i2 * 8 + e] = (f16)v;
        }
    }
}

// ---------------- pairwise bias MLP, MFMA + 4x table reuse ----------------
__global__ void __launch_bounds__(256, 4) k_mlp4(const float* __restrict__ qc, const float* __restrict__ kc,
                                                 const f16x8* __restrict__ W1tab,   // [48][64]
                                                 const f16x8* __restrict__ W2tab,   // [24][64]
                                                 const float* __restrict__ b2,
                                                 float* __restrict__ bias_out) {
    int t = threadIdx.x, lane = t & 63, w = t >> 6;
    int hi = lane >> 4, m = lane & 15;
    int p0 = blockIdx.x * 256 + w * 64;    // wave's 64 pairs, 4 subtiles of 16

    f16x8 rf[4];
#pragma unroll
    for (int s = 0; s < 4; ++s) {
        int pair = p0 + s * 16 + m;
        int qi = pair >> 9, ki = pair & 511;
        float dx = qc[2 * qi] - kc[2 * ki];
        float dy = qc[2 * qi + 1] - kc[2 * ki + 1];
        union { f16x8 v; pk16 h2[4]; } u;
        f16x8 z = {};
        u.v = z;
        if (hi == 0) {
            u.h2[0] = __builtin_amdgcn_cvt_pkrtz(dx, dy);
            u.h2[1] = __builtin_amdgcn_cvt_pkrtz(fabsf(dx), fabsf(dy));
            u.h2[2] = __builtin_amdgcn_cvt_pkrtz(dx * dx, dy * dy);
            u.h2[3] = __builtin_amdgcn_cvt_pkrtz(1.0f, 0.0f);
        }
        rf[s] = u.v;
    }

    float b2h = (m < 12) ? b2[m] : 0.f;
    f32x4 acc[4];
#pragma unroll
    for (int s = 0; s < 4; ++s) { f32x4 a = {b2h, b2h, b2h, b2h}; acc[s] = a; }
    const f32x4 zero = {};
    const f16x8* w1p = W1tab + lane;
    const f16x8* w2p = W2tab + lane;

    for (int j = 0; j < 24; ++j) {
        f16x8 a0  = w1p[(2 * j) * 64];
        f16x8 a1  = w1p[(2 * j + 1) * 64];
        f16x8 w2v = w2p[j * 64];
#pragma unroll
        for (int s = 0; s < 4; ++s) {
            f32x4 pre0 = MFMA16H(a0, rf[s], zero, 0, 0, 0);
            f32x4 pre1 = MFMA16H(a1, rf[s], zero, 0, 0, 0);
            float g0 = gelu_f(pre0[0]), g1 = gelu_f(pre0[1]);
            float g2 = gelu_f(pre0[2]), g3 = gelu_f(pre0[3]);
            float g4 = gelu_f(pre1[0]), g5 = gelu_f(pre1[1]);
            float g6 = gelu_f(pre1[2]), g7 = gelu_f(pre1[3]);
            union { f16x8 v; pk16 h2[4]; } pa;
            pa.h2[0] = __builtin_amdgcn_cvt_pkrtz(g0, g1);
            pa.h2[1] = __builtin_amdgcn_cvt_pkrtz(g2, g3);
            pa.h2[2] = __builtin_amdgcn_cvt_pkrtz(g4, g5);
            pa.h2[3] = __builtin_amdgcn_cvt_pkrtz(g6, g7);
            acc[s] = MFMA16H(pa.v, w2v, acc[s], 0, 0, 0);
        }
    }
    // D: col=lane&15=h, row=hi*4+r = pair-local
    if (m < 12) {
#pragma unroll
        for (int s = 0; s < 4; ++s) {
            float4 o4 = {acc[s][0], acc[s][1], acc[s][2], acc[s][3]};
            *reinterpret_cast<float4*>(bias_out + m * (SEQ * SEQ) + p0 + s * 16 + hi * 4) = o4;
        }
    }
}

// ---------------- GEMM: C[m][n] = sum_k X[m][k]*WT[n][k] + bias[n] (f16 in) ----------------
// MODE 0: store f16 to [B][NH][SEQ][HD];  MODE 1: store f32 row-major [m][n]
template <int MODE>
__global__ void __launch_bounds__(256) k_gemm(const f16* __restrict__ X,
                                              const f16* __restrict__ WT,
                                              const float* __restrict__ bias, void* __restrict__ out) {
    int m0 = blockIdx.x * 64, n0 = blockIdx.y * 64;
    int t = threadIdx.x, lane = t & 63, w = t >> 6;
    int rt2 = w >> 1, ct2 = w & 1;
    int lrow = lane & 15, hi = lane >> 4;
    f32x4 acc[2][2] = {};
    const f16* Xp = X + (m0 + rt2 * 32 + lrow) * DIM + hi * 8;
    const f16* Wp = WT + (n0 + ct2 * 32 + lrow) * DIM + hi * 8;
#pragma unroll 4
    for (int k0 = 0; k0 < DIM; k0 += 32) {
        f16x8 a0 = *(const f16x8*)(Xp + k0);
        f16x8 a1 = *(const f16x8*)(Xp + 16 * DIM + k0);
        f16x8 b0 = *(const f16x8*)(Wp + k0);
        f16x8 b1 = *(const f16x8*)(Wp + 16 * DIM + k0);
        acc[0][0] = MFMA16H(a0, b0, acc[0][0], 0, 0, 0);
        acc[0][1] = MFMA16H(a0, b1, acc[0][1], 0, 0, 0);
        acc[1][0] = MFMA16H(a1, b0, acc[1][0], 0, 0, 0);
        acc[1][1] = MFMA16H(a1, b1, acc[1][1], 0, 0, 0);
    }
#pragma unroll
    for (int rr = 0; rr < 2; ++rr)
#pragma unroll
        for (int cc = 0; cc < 2; ++cc) {
            int n = n0 + ct2 * 32 + cc * 16 + lrow;
            float bn = bias[n];
#pragma unroll
            for (int r = 0; r < 4; ++r) {
                int m = m0 + rt2 * 32 + rr * 16 + hi * 4 + r;
                float v = acc[rr][cc][r] + bn;
                if (MODE == 0) {
                    int bb = m >> 9, l = m & 511, h = n >> 6, d = n & 63;
                    ((f16*)out)[(((bb * NH + h) * SEQ) + l) * HD + d] = (f16)v;
                } else {
                    ((float*)out)[m * DIM + n] = v;
                }
            }
        }
}

// ---------------- transpose V: [B,H,SEQ,HD] -> [B,H,HD,SEQ] (f16 bits) ----------------
__global__ void k_vt(const unsigned short* __restrict__ v_ws, unsigned short* __restrict__ v_t) {
    int bh = blockIdx.x;
    int lk0 = blockIdx.y * 64;
    int t = threadIdx.x;
    const unsigned short* src = v_ws + bh * SEQ * HD;
    unsigned short* dst = v_t + bh * HD * SEQ;
#pragma unroll
    for (int i = 0; i < 2; ++i) {
        int e = i * 256 + t;            // 0..511
        int dh = e >> 3, c8 = e & 7;
        unsigned short tmp[8];
#pragma unroll
        for (int j = 0; j < 8; ++j)
            tmp[j] = src[(lk0 + c8 * 8 + j) * HD + dh];
        *(uint4*)(dst + dh * SEQ + lk0 + c8 * 8) = *(uint4*)tmp;
    }
}

// ---------------- attention: per (qtile16, h, b) ----------------
__global__ void __launch_bounds__(256) k_attn2(const f16* __restrict__ q_ws,
                                               const f16* __restrict__ k_ws,
                                               const f16* __restrict__ v_t,
                                               const float* __restrict__ bias_ws,
                                               f16* __restrict__ attn_out) {
    __shared__ float sm[16 * 516 + 16];   // logits [16][516] + inv[16]  (~33KB)
    int qt = blockIdx.x, h = blockIdx.y, b = blockIdx.z;
    int q0 = qt * 16;
    int t = threadIdx.x, lane = t & 63, w = t >> 6;
    int lrow = lane & 15, hi = lane >> 4;
    int bh = b * NH + h;
    const f16* Q = q_ws + (bh * SEQ + q0) * HD;
    const f16* K = k_ws + bh * SEQ * HD;
    const float* Bias = bias_ws + (h * SEQ + q0) * SEQ;

    // phase A: S = Q K^T * SCALE + bias -> LDS (wave w owns cols [w*128, +128))
    f16x8 aq[2];
#pragma unroll
    for (int ds = 0; ds < 2; ++ds)
        aq[ds] = *(const f16x8*)(Q + lrow * HD + ds * 32 + hi * 8);

#pragma unroll
    for (int ct = 0; ct < 8; ++ct) {
        f32x4 acc0 = {};
        int kk = w * 128 + ct * 16 + lrow;
#pragma unroll
        for (int ds = 0; ds < 2; ++ds) {
            f16x8 bk = *(const f16x8*)(K + kk * HD + ds * 32 + hi * 8);
            acc0 = MFMA16H(aq[ds], bk, acc0, 0, 0, 0);
        }
#pragma unroll
        for (int r = 0; r < 4; ++r) {
            int row0 = hi * 4 + r;
            sm[row0 * 516 + kk] = acc0[r] * SCALE + Bias[row0 * SEQ + kk];
        }
    }
    __syncthreads();

    // phase B: row softmax (16 lanes per row, stride-16 column scan)
    {
        int row = t >> 4, seg = t & 15;
        float mx = -1e30f;
#pragma unroll 8
        for (int i = 0; i < 32; ++i)
            mx = fmaxf(mx, sm[row * 516 + seg + 16 * i]);
        mx = fmaxf(mx, __shfl_xor(mx, 1, 16));
        mx = fmaxf(mx, __shfl_xor(mx, 2, 16));
        mx = fmaxf(mx, __shfl_xor(mx, 4, 16));
        mx = fmaxf(mx, __shfl_xor(mx, 8, 16));
        float s = 0.f;
#pragma unroll 8
        for (int i = 0; i < 32; ++i) {
            int idx = row * 516 + seg + 16 * i;
            float pe = __builtin_amdgcn_exp2f((sm[idx] - mx) * 1.442695041f);
            sm[idx] = pe;
            s += pe;
        }
        s += __shfl_xor(s, 1, 16);
        s += __shfl_xor(s, 2, 16);
        s += __shfl_xor(s, 4, 16);
        s += __shfl_xor(s, 8, 16);
        if (seg == 0) sm[16 * 516 + row] = 1.0f / s;
    }
    __syncthreads();

    // phase C: O = P V  (wave w owns dh cols [w*16, +16))
    const f16* Vt = v_t + bh * HD * SEQ + (w * 16 + lrow) * SEQ;
    f32x4 oacc = {};
    for (int kt = 0; kt < 16; ++kt) {
        f16x8 bv = *(const f16x8*)(Vt + kt * 32 + hi * 8);
        const float* ps = &sm[lrow * 516 + kt * 32 + hi * 8];
        float4 p0 = *(const float4*)(ps);
        float4 p1 = *(const float4*)(ps + 4);
        union { f16x8 v; pk16 h2[4]; } pa;
        pa.h2[0] = __builtin_amdgcn_cvt_pkrtz(p0.x, p0.y);
        pa.h2[1] = __builtin_amdgcn_cvt_pkrtz(p0.z, p0.w);
        pa.h2[2] = __builtin_amdgcn_cvt_pkrtz(p1.x, p1.y);
        pa.h2[3] = __builtin_amdgcn_cvt_pkrtz(p1.z, p1.w);
        oacc = MFMA16H(pa.v, bv, oacc, 0, 0, 0);
    }
#pragma unroll
    for (int r = 0; r < 4; ++r) {
        int row0 = hi * 4 + r;
        float v0 = oacc[r] * sm[16 * 516 + row0];
        attn_out[(b * SEQ + q0 + row0) * DIM + h * HD + w * 16 + lrow] = (f16)v0;
    }
}

extern "C" void kernel_launch(void* const* d_in, const int* in_sizes, int n_in,
                              void* d_out, int out_size, void* d_ws, size_t ws_size,
                              hipStream_t stream) {
    const float* query     = (const float*)d_in[0];
    const float* key_value = (const float*)d_in[1];
    const float* qc        = (const float*)d_in[2];
    const float* kc        = (const float*)d_in[3];
    const float* Wq        = (const float*)d_in[4];
    const float* bq        = (const float*)d_in[5];
    const float* Wk        = (const float*)d_in[6];
    const float* bk        = (const float*)d_in[7];
    const float* Wv        = (const float*)d_in[8];
    const float* bv        = (const float*)d_in[9];
    const float* Wo        = (const float*)d_in[10];
    const float* bo        = (const float*)d_in[11];
    const float* W1        = (const float*)d_in[12];
    const float* b1        = (const float*)d_in[13];
    const float* W2        = (const float*)d_in[14];
    const float* b2        = (const float*)d_in[15];

    char* ws = (char*)d_ws;
    f16* Xq   = (f16*)(ws + 0);          // reused as attn_out
    f16* Xkv  = (f16*)(ws + 6291456);    // reused as v_t
    f16* WqT  = (f16*)(ws + 12582912);
    f16* WkT  = (f16*)(ws + 13762560);
    f16* WvT  = (f16*)(ws + 14942208);
    f16* WoT  = (f16*)(ws + 16121856);
    f16* q_ws = (f16*)(ws + 17301504);
    f16* k_ws = (f16*)(ws + 23592960);
    f16* v_ws = (f16*)(ws + 29884416);
    float* bias_ws = (float*)(ws + 36175872);          // 12582912 B
    f16* W1tab     = (f16*)(ws + 17301504);            // in dead q_ws region
    f16* W2tab     = (f16*)(ws + 17350656);
    f16* attn_out  = Xq;   // Xq dead after Q projection
    f16* v_t       = Xkv;  // Xkv dead after K/V projections

    k_cvt16<<<dim3(1536), dim3(256), 0, stream>>>(query, Xq, 393216);
    k_cvt16<<<dim3(1536), dim3(256), 0, stream>>>(key_value, Xkv, 393216);
    k_wt<<<dim3(24, 24), dim3(32, 8), 0, stream>>>(Wq, WqT);
    k_wt<<<dim3(24, 24), dim3(32, 8), 0, stream>>>(Wk, WkT);
    k_wt<<<dim3(24, 24), dim3(32, 8), 0, stream>>>(Wv, WvT);
    k_wt<<<dim3(24, 24), dim3(32, 8), 0, stream>>>(Wo, WoT);
    k_pack3<<<dim3(18), dim3(256), 0, stream>>>(W1, b1, W2, W1tab, W2tab);
    k_mlp4<<<dim3(1024), dim3(256), 0, stream>>>(qc, kc, (const f16x8*)W1tab, (const f16x8*)W2tab, b2, bias_ws);
    k_gemm<0><<<dim3(64, 12), dim3(256), 0, stream>>>(Xq, WqT, bq, q_ws);
    k_gemm<0><<<dim3(64, 12), dim3(256), 0, stream>>>(Xkv, WkT, bk, k_ws);
    k_gemm<0><<<dim3(64, 12), dim3(256), 0, stream>>>(Xkv, WvT, bv, v_ws);
    k_vt<<<dim3(96, 8), dim3(256), 0, stream>>>((const unsigned short*)v_ws, (unsigned short*)v_t);
    k_attn2<<<dim3(32, NH, NB), dim3(256), 0, stream>>>(q_ws, k_ws, v_t, bias_ws, attn_out);
    k_gemm<1><<<dim3(64, 12), dim3(256), 0, stream>>>(attn_out, WoT, bo, d_out);
}

// Round 5
// 182.618 us; speedup vs baseline: 1.5727x; 1.5727x over previous
//
#include <hip/hip_runtime.h>
#include <hip/hip_bf16.h>
#include <stdint.h>

typedef __attribute__((ext_vector_type(4))) float f32x4;
typedef _Float16 f16;
typedef __attribute__((ext_vector_type(8))) _Float16 f16x8;
typedef decltype(__builtin_amdgcn_cvt_pkrtz(0.f, 0.f)) pk16;

#define DIM   768
#define NH    12
#define HD    64
#define NB    8
#define SEQ   512
#define SCALE 0.125f

#define MFMA16H __builtin_amdgcn_mfma_f32_16x16x32_f16

// gelu tanh-approx: x * sigmoid(2*0.7978845608*(x + 0.044715 x^3))
__device__ __forceinline__ float gelu_f(float x) {
    float pp = x * x;
    float poly = __builtin_fmaf(pp, -0.1029433f, -2.3022077f);
    float ev = __builtin_amdgcn_exp2f(x * poly);
    return x * __builtin_amdgcn_rcpf(1.0f + ev);
}

// ---------------- prep: f32 -> f16 convert (8 elems/thread) ----------------
__global__ void k_cvt16(const float* __restrict__ in, f16* __restrict__ out, int n8) {
    int i = blockIdx.x * blockDim.x + threadIdx.x;
    if (i >= n8) return;
    const float4* s = reinterpret_cast<const float4*>(in + i * 8);
    float4 f0 = s[0], f1 = s[1];
    union { pk16 h[4]; uint4 v; } o;
    o.h[0] = __builtin_amdgcn_cvt_pkrtz(f0.x, f0.y);
    o.h[1] = __builtin_amdgcn_cvt_pkrtz(f0.z, f0.w);
    o.h[2] = __builtin_amdgcn_cvt_pkrtz(f1.x, f1.y);
    o.h[3] = __builtin_amdgcn_cvt_pkrtz(f1.z, f1.w);
    reinterpret_cast<uint4*>(out)[i] = o.v;
}

// ---------------- prep: W[768][768] f32 -> WT[768][768] f16 (transposed) ----------------
__global__ void k_wt(const float* __restrict__ W, f16* __restrict__ WT) {
    __shared__ float t[32][33];
    int n0 = blockIdx.x * 32, k0 = blockIdx.y * 32;
    int tx = threadIdx.x, ty = threadIdx.y; // 32 x 8
#pragma unroll
    for (int j = 0; j < 4; ++j)
        t[ty + 8 * j][tx] = W[(k0 + ty + 8 * j) * DIM + n0 + tx];
    __syncthreads();
#pragma unroll
    for (int j = 0; j < 4; ++j)
        WT[(n0 + ty + 8 * j) * DIM + k0 + tx] = (f16)t[tx][ty + 8 * j];
}

// ---------------- prep: pack MLP param tables (f16 MFMA fragments) ----------------
__global__ void k_pack3(const float* __restrict__ W1, const float* __restrict__ b1,
                        const float* __restrict__ W2, f16* __restrict__ W1tab,
                        f16* __restrict__ W2tab) {
    int i = blockIdx.x * 256 + threadIdx.x;
    if (i < 3072) {
        int lane = i & 63;
        int hi = lane >> 4, m = lane & 15;
        int u = (i >> 6) * 16 + m;
#pragma unroll
        for (int e = 0; e < 8; ++e) {
            float v = 0.f;
            if (hi == 0) {
                if (e < 6) v = W1[e * DIM + u];
                else if (e == 6) v = b1[u];
            }
            W1tab[i * 8 + e] = (f16)v;
        }
    } else if (i < 4608) {
        int i2 = i - 3072;
        int j = i2 >> 6, lane = i2 & 63;
        int g = lane >> 4, h = lane & 15;
#pragma unroll
        for (int e = 0; e < 8; ++e) {
            int u = 32 * j + ((e >> 2) << 4) + (g << 2) + (e & 3);
            float v = (h < 12) ? W2[u * 12 + h] : 0.f;
            W2tab[i2 * 8 + e] = (f16)v;
        }
    }
}

// ---------------- pairwise bias MLP (MFMA), f16 output ----------------
__global__ void __launch_bounds__(256) k_mlp5(const float* __restrict__ qc, const float* __restrict__ kc,
                                              const f16x8* __restrict__ W1tab,   // [48][64]
                                              const f16x8* __restrict__ W2tab,   // [24][64]
                                              const float* __restrict__ b2,
                                              f16* __restrict__ bias16) {
    int t = threadIdx.x, lane = t & 63, w = t >> 6;
    int hi = lane >> 4, m = lane & 15;
    int p0 = blockIdx.x * 64 + w * 16;
    int pair = p0 + m;
    int qi = pair >> 9, ki = pair & 511;
    float dx = qc[2 * qi] - kc[2 * ki];
    float dy = qc[2 * qi + 1] - kc[2 * ki + 1];

    union { f16x8 v; pk16 h2[4]; } rf;
    { f16x8 z = {}; rf.v = z; }
    if (hi == 0) {
        rf.h2[0] = __builtin_amdgcn_cvt_pkrtz(dx, dy);
        rf.h2[1] = __builtin_amdgcn_cvt_pkrtz(fabsf(dx), fabsf(dy));
        rf.h2[2] = __builtin_amdgcn_cvt_pkrtz(dx * dx, dy * dy);
        rf.h2[3] = __builtin_amdgcn_cvt_pkrtz(1.0f, 0.0f);
    }

    float b2h = (m < 12) ? b2[m] : 0.f;
    f32x4 acc = {b2h, b2h, b2h, b2h};
    const f32x4 zero = {};
    const f16x8* w1p = W1tab + lane;
    const f16x8* w2p = W2tab + lane;

#pragma unroll 2
    for (int j = 0; j < 24; ++j) {
        f16x8 a0  = w1p[(2 * j) * 64];
        f16x8 a1  = w1p[(2 * j + 1) * 64];
        f16x8 w2v = w2p[j * 64];
        f32x4 pre0 = MFMA16H(a0, rf.v, zero, 0, 0, 0);
        f32x4 pre1 = MFMA16H(a1, rf.v, zero, 0, 0, 0);
        float g0 = gelu_f(pre0[0]), g1 = gelu_f(pre0[1]);
        float g2 = gelu_f(pre0[2]), g3 = gelu_f(pre0[3]);
        float g4 = gelu_f(pre1[0]), g5 = gelu_f(pre1[1]);
        float g6 = gelu_f(pre1[2]), g7 = gelu_f(pre1[3]);
        union { f16x8 v; pk16 h2[4]; } pa;
        pa.h2[0] = __builtin_amdgcn_cvt_pkrtz(g0, g1);
        pa.h2[1] = __builtin_amdgcn_cvt_pkrtz(g2, g3);
        pa.h2[2] = __builtin_amdgcn_cvt_pkrtz(g4, g5);
        pa.h2[3] = __builtin_amdgcn_cvt_pkrtz(g6, g7);
        acc = MFMA16H(pa.v, w2v, acc, 0, 0, 0);
    }
    if (m < 12) {
        union { pk16 h[2]; uint2 u2; } o;
        o.h[0] = __builtin_amdgcn_cvt_pkrtz(acc[0], acc[1]);
        o.h[1] = __builtin_amdgcn_cvt_pkrtz(acc[2], acc[3]);
        *reinterpret_cast<uint2*>(bias16 + m * (SEQ * SEQ) + p0 + hi * 4) = o.u2;
    }
}

// ---------------- LDS-staged GEMM: 128x128 tile, BK=32, double-buffered ----------------
// C[m][n] = sum_k X[m][k]*WT[n][k] + bias[n]
// MODE 0: store f16 to [B][NH][SEQ][HD];  MODE 1: store f32 row-major [m][n]
struct GArgs { const f16* X; const f16* W; const float* bias; void* out; };
struct G3 { GArgs a[3]; };

template <int MODE>
__global__ void __launch_bounds__(256) k_gemm3(G3 args) {
    __shared__ uint4 lds[2048];   // buf b: A at b*1024 (512), B at b*1024+512
    GArgs ga = args.a[blockIdx.z];
    int m0 = blockIdx.x * 128, n0 = blockIdx.y * 128;
    int t = threadIdx.x, lane = t & 63, w = t >> 6;
    int wr = w >> 1, wc = w & 1;
    int lm = lane & 15, hi = lane >> 4;

    // staging: thread t covers row = t>>1, 32B chunk sch = t&1 (two b128 slots)
    int srow = t >> 1, sch = t & 1;
    const f16* Ag = ga.X + (m0 + srow) * DIM + sch * 16;
    const f16* Bg = ga.W + (n0 + srow) * DIM + sch * 16;
    int sw = (srow >> 1) & 3;
    int wiA0 = srow * 4 + ((2 * sch) ^ sw);
    int wiA1 = srow * 4 + ((2 * sch + 1) ^ sw);

    // read offsets (uint4 index): row*4 + (hi ^ ((row>>1)&3))
    int aidx[4], bidx[4];
#pragma unroll
    for (int i = 0; i < 4; ++i) {
        int ar = wr * 64 + i * 16 + lm;
        aidx[i] = ar * 4 + (hi ^ ((ar >> 1) & 3));
        int br = wc * 64 + i * 16 + lm;
        bidx[i] = 512 + br * 4 + (hi ^ ((br >> 1) & 3));
    }

    f32x4 acc[4][4] = {};

    { // prologue: stage kt=0
        uint4 a0 = *(const uint4*)(Ag);
        uint4 a1 = *(const uint4*)(Ag + 8);
        uint4 b0 = *(const uint4*)(Bg);
        uint4 b1 = *(const uint4*)(Bg + 8);
        lds[wiA0] = a0; lds[wiA1] = a1;
        lds[512 + wiA0] = b0; lds[512 + wiA1] = b1;
    }
    __syncthreads();

    for (int kt = 0; kt < 24; ++kt) {
        uint4 na0, na1, nb0, nb1;
        bool pf = kt < 23;
        if (pf) {
            const f16* An = Ag + (kt + 1) * 32;
            const f16* Bn = Bg + (kt + 1) * 32;
            na0 = *(const uint4*)(An);
            na1 = *(const uint4*)(An + 8);
            nb0 = *(const uint4*)(Bn);
            nb1 = *(const uint4*)(Bn + 8);
        }
        int bo = (kt & 1) << 10;
        f16x8 af[4], bf[4];
#pragma unroll
        for (int i = 0; i < 4; ++i) {
            af[i] = *(const f16x8*)&lds[bo + aidx[i]];
            bf[i] = *(const f16x8*)&lds[bo + bidx[i]];
        }
#pragma unroll
        for (int mi = 0; mi < 4; ++mi)
#pragma unroll
            for (int ni = 0; ni < 4; ++ni)
                acc[mi][ni] = MFMA16H(af[mi], bf[ni], acc[mi][ni], 0, 0, 0);
        if (pf) {
            __syncthreads();
            int bo2 = bo ^ 1024;
            lds[bo2 + wiA0] = na0; lds[bo2 + wiA1] = na1;
            lds[bo2 + 512 + wiA0] = nb0; lds[bo2 + 512 + wiA1] = nb1;
            __syncthreads();
        }
    }

#pragma unroll
    for (int mi = 0; mi < 4; ++mi)
#pragma unroll
        for (int ni = 0; ni < 4; ++ni) {
            int n = n0 + wc * 64 + ni * 16 + lm;
            float bn = ga.bias[n];
#pragma unroll
            for (int r = 0; r < 4; ++r) {
                int m = m0 + wr * 64 + mi * 16 + hi * 4 + r;
                float v = acc[mi][ni][r] + bn;
                if (MODE == 0) {
                    int bb = m >> 9, l = m & 511, h = n >> 6, d = n & 63;
                    ((f16*)ga.out)[(((bb * NH + h) * SEQ) + l) * HD + d] = (f16)v;
                } else {
                    ((float*)ga.out)[m * DIM + n] = v;
                }
            }
        }
}

// ---------------- transpose V: [B,H,SEQ,HD] -> [B,H,HD,SEQ] (f16 bits) ----------------
__global__ void k_vt(const unsigned short* __restrict__ v_ws, unsigned short* __restrict__ v_t) {
    int bh = blockIdx.x;
    int lk0 = blockIdx.y * 64;
    int t = threadIdx.x;
    const unsigned short* src = v_ws + bh * SEQ * HD;
    unsigned short* dst = v_t + bh * HD * SEQ;
#pragma unroll
    for (int i = 0; i < 2; ++i) {
        int e = i * 256 + t;            // 0..511
        int dh = e >> 3, c8 = e & 7;
        unsigned short tmp[8];
#pragma unroll
        for (int j = 0; j < 8; ++j)
            tmp[j] = src[(lk0 + c8 * 8 + j) * HD + dh];
        *(uint4*)(dst + dh * SEQ + lk0 + c8 * 8) = *(uint4*)tmp;
    }
}

// ---------------- attention: per (qtile32, h, b), f16 internals ----------------
__global__ void __launch_bounds__(256) k_attn3(const f16* __restrict__ q_ws,
                                               const f16* __restrict__ k_ws,
                                               const f16* __restrict__ v_t,
                                               const f16* __restrict__ bias16,
                                               f16* __restrict__ attn_out) {
    __shared__ float sm[32 * 516 + 32];   // logits [32][516] + inv[32]
    int qt = blockIdx.x, h = blockIdx.y, b = blockIdx.z;
    int q0 = qt * 32;
    int t = threadIdx.x, lane = t & 63, w = t >> 6;
    int lrow = lane & 15, hi = lane >> 4;
    int bh = b * NH + h;
    const f16* Q = q_ws + (bh * SEQ + q0) * HD;
    const f16* K = k_ws + bh * SEQ * HD;
    const f16* Bias = bias16 + (h * SEQ + q0) * SEQ;

    // phase A: S = Q K^T * SCALE + bias -> LDS (wave w owns cols [w*128, +128))
    f16x8 aq[2][2];
#pragma unroll
    for (int rt = 0; rt < 2; ++rt)
#pragma unroll
        for (int ds = 0; ds < 2; ++ds)
            aq[rt][ds] = *(const f16x8*)(Q + (rt * 16 + lrow) * HD + ds * 32 + hi * 8);

#pragma unroll
    for (int ct = 0; ct < 8; ++ct) {
        f32x4 acc0 = {}, acc1 = {};
        int kk = w * 128 + ct * 16 + lrow;
#pragma unroll
        for (int ds = 0; ds < 2; ++ds) {
            f16x8 bk = *(const f16x8*)(K + kk * HD + ds * 32 + hi * 8);
            acc0 = MFMA16H(aq[0][ds], bk, acc0, 0, 0, 0);
            acc1 = MFMA16H(aq[1][ds], bk, acc1, 0, 0, 0);
        }
#pragma unroll
        for (int r = 0; r < 4; ++r) {
            int row0 = hi * 4 + r;
            sm[row0 * 516 + kk] = acc0[r] * SCALE + (float)Bias[row0 * SEQ + kk];
            int row1 = 16 + hi * 4 + r;
            sm[row1 * 516 + kk] = acc1[r] * SCALE + (float)Bias[row1 * SEQ + kk];
        }
    }
    __syncthreads();

    // phase B: row softmax (8 lanes per row, stride-8 column scan)
    {
        int row = t >> 3, seg = t & 7;
        float mx = -1e30f;
#pragma unroll 8
        for (int i = 0; i < 64; ++i)
            mx = fmaxf(mx, sm[row * 516 + seg + 8 * i]);
        mx = fmaxf(mx, __shfl_xor(mx, 1));
        mx = fmaxf(mx, __shfl_xor(mx, 2));
        mx = fmaxf(mx, __shfl_xor(mx, 4));
        float s = 0.f;
#pragma unroll 8
        for (int i = 0; i < 64; ++i) {
            int idx = row * 516 + seg + 8 * i;
            float pe = __builtin_amdgcn_exp2f((sm[idx] - mx) * 1.442695041f);
            sm[idx] = pe;
            s += pe;
        }
        s += __shfl_xor(s, 1);
        s += __shfl_xor(s, 2);
        s += __shfl_xor(s, 4);
        if (seg == 0) sm[32 * 516 + row] = 1.0f / s;
    }
    __syncthreads();

    // phase C: O = P V  (wave w owns dh cols [w*16, +16))
    const f16* Vt = v_t + bh * HD * SEQ + (w * 16 + lrow) * SEQ;
    f32x4 oacc0 = {}, oacc1 = {};
    for (int kt = 0; kt < 16; ++kt) {
        f16x8 bv = *(const f16x8*)(Vt + kt * 32 + hi * 8);
#pragma unroll
        for (int rt = 0; rt < 2; ++rt) {
            const float* ps = &sm[(rt * 16 + lrow) * 516 + kt * 32 + hi * 8];
            float4 p0 = *(const float4*)(ps);
            float4 p1 = *(const float4*)(ps + 4);
            union { f16x8 v; pk16 h2[4]; } pa;
            pa.h2[0] = __builtin_amdgcn_cvt_pkrtz(p0.x, p0.y);
            pa.h2[1] = __builtin_amdgcn_cvt_pkrtz(p0.z, p0.w);
            pa.h2[2] = __builtin_amdgcn_cvt_pkrtz(p1.x, p1.y);
            pa.h2[3] = __builtin_amdgcn_cvt_pkrtz(p1.z, p1.w);
            if (rt == 0) oacc0 = MFMA16H(pa.v, bv, oacc0, 0, 0, 0);
            else         oacc1 = MFMA16H(pa.v, bv, oacc1, 0, 0, 0);
        }
    }
#pragma unroll
    for (int r = 0; r < 4; ++r) {
        int row0 = hi * 4 + r;
        float v0 = oacc0[r] * sm[32 * 516 + row0];
        attn_out[(b * SEQ + q0 + row0) * DIM + h * HD + w * 16 + lrow] = (f16)v0;
        int row1 = 16 + hi * 4 + r;
        float v1 = oacc1[r] * sm[32 * 516 + row1];
        attn_out[(b * SEQ + q0 + row1) * DIM + h * HD + w * 16 + lrow] = (f16)v1;
    }
}

extern "C" void kernel_launch(void* const* d_in, const int* in_sizes, int n_in,
                              void* d_out, int out_size, void* d_ws, size_t ws_size,
                              hipStream_t stream) {
    const float* query     = (const float*)d_in[0];
    const float* key_value = (const float*)d_in[1];
    const float* qc        = (const float*)d_in[2];
    const float* kc        = (const float*)d_in[3];
    const float* Wq        = (const float*)d_in[4];
    const float* bq        = (const float*)d_in[5];
    const float* Wk        = (const float*)d_in[6];
    const float* bk        = (const float*)d_in[7];
    const float* Wv        = (const float*)d_in[8];
    const float* bv        = (const float*)d_in[9];
    const float* Wo        = (const float*)d_in[10];
    const float* bo        = (const float*)d_in[11];
    const float* W1        = (const float*)d_in[12];
    const float* b1        = (const float*)d_in[13];
    const float* W2        = (const float*)d_in[14];
    const float* b2        = (const float*)d_in[15];

    char* ws = (char*)d_ws;
    f16* Xq   = (f16*)(ws + 0);          // reused as attn_out
    f16* Xkv  = (f16*)(ws + 6291456);    // reused as v_t
    f16* WqT  = (f16*)(ws + 12582912);
    f16* WkT  = (f16*)(ws + 13762560);
    f16* WvT  = (f16*)(ws + 14942208);
    f16* WoT  = (f16*)(ws + 16121856);
    f16* q_ws = (f16*)(ws + 17301504);
    f16* k_ws = (f16*)(ws + 23592960);
    f16* v_ws = (f16*)(ws + 29884416);
    f16* bias16    = (f16*)(ws + 36175872);            // 6291456 B
    f16* W1tab     = (f16*)(ws + 42467328);
    f16* W2tab     = (f16*)(ws + 42516480);
    f16* attn_out  = Xq;   // Xq dead after Q projection
    f16* v_t       = Xkv;  // Xkv dead after K/V projections

    k_cvt16<<<dim3(1536), dim3(256), 0, stream>>>(query, Xq, 393216);
    k_cvt16<<<dim3(1536), dim3(256), 0, stream>>>(key_value, Xkv, 393216);
    k_wt<<<dim3(24, 24), dim3(32, 8), 0, stream>>>(Wq, WqT);
    k_wt<<<dim3(24, 24), dim3(32, 8), 0, stream>>>(Wk, WkT);
    k_wt<<<dim3(24, 24), dim3(32, 8), 0, stream>>>(Wv, WvT);
    k_wt<<<dim3(24, 24), dim3(32, 8), 0, stream>>>(Wo, WoT);
    k_pack3<<<dim3(18), dim3(256), 0, stream>>>(W1, b1, W2, W1tab, W2tab);
    k_mlp5<<<dim3(4096), dim3(256), 0, stream>>>(qc, kc, (const f16x8*)W1tab, (const f16x8*)W2tab, b2, bias16);

    G3 qkv;
    qkv.a[0] = {Xq,  WqT, bq, (void*)q_ws};
    qkv.a[1] = {Xkv, WkT, bk, (void*)k_ws};
    qkv.a[2] = {Xkv, WvT, bv, (void*)v_ws};
    k_gemm3<0><<<dim3(32, 6, 3), dim3(256), 0, stream>>>(qkv);

    k_vt<<<dim3(96, 8), dim3(256), 0, stream>>>((const unsigned short*)v_ws, (unsigned short*)v_t);
    k_attn3<<<dim3(16, NH, NB), dim3(256), 0, stream>>>(q_ws, k_ws, v_t, bias16, attn_out);

    G3 oproj;
    oproj.a[0] = {attn_out, WoT, bo, d_out};
    oproj.a[1] = oproj.a[0];
    oproj.a[2] = oproj.a[0];
    k_gemm3<1><<<dim3(32, 6, 1), dim3(256), 0, stream>>>(oproj);
}